// Round 1
// baseline (86.220 us; speedup 1.0000x reference)
//
#include <hip/hip_runtime.h>

// PullbackMetric: G[x,y,m,n] = dmu_m^T Si dmu_n + 0.5*tr(Si dSig_m Si dSig_n)
// Grid 512x512, D=8, periodic central differences, output (512,512,2,2).

constexpr int GX = 512;
constexpr int GY = 512;

// C = A * B, 8x8 row-major flat arrays, fully unrolled
#define MATMUL8(Cm, Am, Bm)                              \
    _Pragma("unroll")                                    \
    for (int i_ = 0; i_ < 8; ++i_) {                     \
        _Pragma("unroll")                                \
        for (int k_ = 0; k_ < 8; ++k_) {                 \
            float acc_ = 0.0f;                           \
            _Pragma("unroll")                            \
            for (int j_ = 0; j_ < 8; ++j_)               \
                acc_ += (Am)[i_*8 + j_] * (Bm)[j_*8 + k_];\
            (Cm)[i_*8 + k_] = acc_;                      \
        }                                                \
    }

__global__ __launch_bounds__(256) void pullback_metric_kernel(
    const float* __restrict__ mu,
    const float* __restrict__ sigma,
    const float* __restrict__ sigma_inv,
    float* __restrict__ out)
{
    const int idx = blockIdx.x * 256 + threadIdx.x;   // 0 .. 512*512-1
    const int x = idx >> 9;
    const int y = idx & 511;
    const int xm = (x - 1) & 511;
    const int xp = (x + 1) & 511;
    const int ym = (y - 1) & 511;
    const int yp = (y + 1) & 511;

    // ---------------- sigma_inv (center), 64 floats ----------------
    float Si[64];
    {
        const float4* p = reinterpret_cast<const float4*>(sigma_inv + (size_t)idx * 64);
        #pragma unroll
        for (int k = 0; k < 16; ++k) {
            float4 v = p[k];
            Si[4*k+0] = v.x; Si[4*k+1] = v.y; Si[4*k+2] = v.z; Si[4*k+3] = v.w;
        }
    }

    // ---------------- dmu + mean terms ----------------
    float mean00, mean01, mean11;
    {
        float dmu0[8], dmu1[8];
        const float4* mxp = reinterpret_cast<const float4*>(mu + (size_t)((xp << 9) | y) * 8);
        const float4* mxm = reinterpret_cast<const float4*>(mu + (size_t)((xm << 9) | y) * 8);
        const float4* myp = reinterpret_cast<const float4*>(mu + (size_t)((x << 9) | yp) * 8);
        const float4* mym = reinterpret_cast<const float4*>(mu + (size_t)((x << 9) | ym) * 8);
        #pragma unroll
        for (int k = 0; k < 2; ++k) {
            float4 a = mxp[k], b = mxm[k], c = myp[k], d = mym[k];
            dmu0[4*k+0] = (a.x - b.x) * 0.5f;
            dmu0[4*k+1] = (a.y - b.y) * 0.5f;
            dmu0[4*k+2] = (a.z - b.z) * 0.5f;
            dmu0[4*k+3] = (a.w - b.w) * 0.5f;
            dmu1[4*k+0] = (c.x - d.x) * 0.5f;
            dmu1[4*k+1] = (c.y - d.y) * 0.5f;
            dmu1[4*k+2] = (c.z - d.z) * 0.5f;
            dmu1[4*k+3] = (c.w - d.w) * 0.5f;
        }
        mean00 = 0.0f; mean01 = 0.0f; mean11 = 0.0f;
        #pragma unroll
        for (int i = 0; i < 8; ++i) {
            float t0 = 0.0f, t1 = 0.0f;
            #pragma unroll
            for (int j = 0; j < 8; ++j) {
                t0 += Si[i*8 + j] * dmu0[j];
                t1 += Si[i*8 + j] * dmu1[j];
            }
            mean00 += dmu0[i] * t0;   // dmu0^T Si dmu0
            mean01 += dmu0[i] * t1;   // dmu0^T Si dmu1
            mean11 += dmu1[i] * t1;   // dmu1^T Si dmu1
        }
    }

    // ---------------- cov terms ----------------
    // A1/A2 are reused scratch matrices; at most {Si, A1, A2} live (192 floats).
    float A1[64], A2[64];

    // dSig_x -> A1
    {
        const float4* sxp = reinterpret_cast<const float4*>(sigma + (size_t)((xp << 9) | y) * 64);
        const float4* sxm = reinterpret_cast<const float4*>(sigma + (size_t)((xm << 9) | y) * 64);
        #pragma unroll
        for (int k = 0; k < 16; ++k) {
            float4 a = sxp[k], b = sxm[k];
            A1[4*k+0] = (a.x - b.x) * 0.5f;
            A1[4*k+1] = (a.y - b.y) * 0.5f;
            A1[4*k+2] = (a.z - b.z) * 0.5f;
            A1[4*k+3] = (a.w - b.w) * 0.5f;
        }
    }

    // T = Si * dSig_x  -> A2
    MATMUL8(A2, Si, A1);

    // cov00 = tr(T*T) = sum_{ik} T[i,k]*T[k,i]
    float cov00 = 0.0f;
    #pragma unroll
    for (int i = 0; i < 8; ++i)
        #pragma unroll
        for (int k = 0; k < 8; ++k)
            cov00 += A2[i*8 + k] * A2[k*8 + i];

    // B = T * Si -> A1   (B = Si dSig_x Si, symmetric)
    MATMUL8(A1, A2, Si);

    // dSig_y -> A2
    {
        const float4* syp = reinterpret_cast<const float4*>(sigma + (size_t)((x << 9) | yp) * 64);
        const float4* sym = reinterpret_cast<const float4*>(sigma + (size_t)((x << 9) | ym) * 64);
        #pragma unroll
        for (int k = 0; k < 16; ++k) {
            float4 a = syp[k], b = sym[k];
            A2[4*k+0] = (a.x - b.x) * 0.5f;
            A2[4*k+1] = (a.y - b.y) * 0.5f;
            A2[4*k+2] = (a.z - b.z) * 0.5f;
            A2[4*k+3] = (a.w - b.w) * 0.5f;
        }
    }

    // cov01 = tr(A_x A_y) = <B, dSig_y>  (B symmetric)
    float cov01 = 0.0f;
    #pragma unroll
    for (int n = 0; n < 64; ++n)
        cov01 += A1[n] * A2[n];

    // U = Si * dSig_y -> A1
    MATMUL8(A1, Si, A2);

    // cov11 = tr(U*U)
    float cov11 = 0.0f;
    #pragma unroll
    for (int i = 0; i < 8; ++i)
        #pragma unroll
        for (int k = 0; k < 8; ++k)
            cov11 += A1[i*8 + k] * A1[k*8 + i];

    // ---------------- output ----------------
    float4 r;
    r.x = mean00 + 0.5f * cov00;   // G[0][0]
    r.y = mean01 + 0.5f * cov01;   // G[0][1]
    r.z = r.y;                     // G[1][0] (symmetric mirror)
    r.w = mean11 + 0.5f * cov11;   // G[1][1]
    reinterpret_cast<float4*>(out)[idx] = r;
}

extern "C" void kernel_launch(void* const* d_in, const int* in_sizes, int n_in,
                              void* d_out, int out_size, void* d_ws, size_t ws_size,
                              hipStream_t stream) {
    const float* mu        = (const float*)d_in[0];
    const float* sigma     = (const float*)d_in[1];
    const float* sigma_inv = (const float*)d_in[2];
    float* out = (float*)d_out;

    const int total = GX * GY;              // 262144 threads, 1 per pixel
    const int block = 256;
    const int grid = (total + block - 1) / block;  // 1024 blocks
    pullback_metric_kernel<<<grid, block, 0, stream>>>(mu, sigma, sigma_inv, out);
}

// Round 4
// 33.423 us; speedup vs baseline: 2.5797x; 2.5797x over previous
//
#include <hip/hip_runtime.h>

// PullbackMetric, 4 threads per pixel (each owns rows {2s, 2s+1} of the 8x8 mats).
// G[m][n] = dmu_m^T Si dmu_n + 0.5 * tr( (Si dSig_m) (Si dSig_n) )
// With T = Si*dSx, U = Si*dSy:
//   cov00 = sum_ik T[i,k]T[k,i], cov01 = sum_ik T[i,k]U[k,i], cov11 = sum_ik U[i,k]U[k,i]
// LDS slots per pixel: slotA (dSx, later overwritten by T), slotB (dSy -> U), slotD (dmu).

constexpr int MSTRIDE = 68;   // 272 B: 16B-aligned, 2-way banking across 16 pixels/wave
constexpr int DSTRIDE = 20;   // 80 B: 16B-aligned, spreads banks

__global__ __launch_bounds__(256, 4) void pm4_kernel(
    const float* __restrict__ mu,
    const float* __restrict__ sigma,
    const float* __restrict__ sigma_inv,
    float* __restrict__ out)
{
    __shared__ float mA[64 * MSTRIDE];   // 17408 B
    __shared__ float mB[64 * MSTRIDE];   // 17408 B
    __shared__ float mD[64 * DSTRIDE];   //  5120 B   (total 39936 B -> 4 blocks/CU)

    const int tid = threadIdx.x;
    const int s   = tid & 3;     // row-pair id: rows 2s, 2s+1
    const int p   = tid >> 2;    // pixel within block (0..63)

    // XCD-aware chunked swizzle: 4096 blocks, 8 XCDs, 512 contiguous logical blocks/XCD
    const int bid = blockIdx.x;
    const int swz = (bid & 7) * 512 + (bid >> 3);
    const int idx = swz * 64 + p;            // pixel 0..262143

    const int x = idx >> 9, y = idx & 511;
    const int ixp = (((x + 1) & 511) << 9) | y;
    const int ixm = (((x - 1) & 511) << 9) | y;
    const int iyp = (x << 9) | ((y + 1) & 511);
    const int iym = (x << 9) | ((y - 1) & 511);

    float* slotA = mA + p * MSTRIDE;
    float* slotB = mB + p * MSTRIDE;
    float* slotD = mD + p * DSTRIDE;

    // ---------------- load Si rows 2s, 2s+1 (16 floats) ----------------
    float Si[16];
    {
        const float4* q = reinterpret_cast<const float4*>(sigma_inv + (size_t)idx * 64 + s * 16);
        #pragma unroll
        for (int k = 0; k < 4; ++k) {
            float4 v = q[k];
            Si[4*k+0] = v.x; Si[4*k+1] = v.y; Si[4*k+2] = v.z; Si[4*k+3] = v.w;
        }
    }

    // ---------------- stage dSx rows -> slotA, dSy rows -> slotB ----------------
    {
        const float4* axp = reinterpret_cast<const float4*>(sigma + (size_t)ixp * 64 + s * 16);
        const float4* axm = reinterpret_cast<const float4*>(sigma + (size_t)ixm * 64 + s * 16);
        const float4* ayp = reinterpret_cast<const float4*>(sigma + (size_t)iyp * 64 + s * 16);
        const float4* aym = reinterpret_cast<const float4*>(sigma + (size_t)iym * 64 + s * 16);
        float4* wA = reinterpret_cast<float4*>(slotA + s * 16);
        float4* wB = reinterpret_cast<float4*>(slotB + s * 16);
        #pragma unroll
        for (int k = 0; k < 4; ++k) {
            float4 a = axp[k], b = axm[k];
            float4 r;
            r.x = (a.x - b.x) * 0.5f; r.y = (a.y - b.y) * 0.5f;
            r.z = (a.z - b.z) * 0.5f; r.w = (a.w - b.w) * 0.5f;
            wA[k] = r;
            float4 c = ayp[k], d = aym[k];
            float4 r2;
            r2.x = (c.x - d.x) * 0.5f; r2.y = (c.y - d.y) * 0.5f;
            r2.z = (c.z - d.z) * 0.5f; r2.w = (c.w - d.w) * 0.5f;
            wB[k] = r2;
        }
    }

    // ---------------- dmu components for rows 2s, 2s+1 -> slotD ----------------
    float d0a, d0b, d1a, d1b;   // dmu0[2s], dmu0[2s+1], dmu1[2s], dmu1[2s+1]
    {
        const float2* mxp = reinterpret_cast<const float2*>(mu + (size_t)ixp * 8 + 2 * s);
        const float2* mxm = reinterpret_cast<const float2*>(mu + (size_t)ixm * 8 + 2 * s);
        const float2* myp = reinterpret_cast<const float2*>(mu + (size_t)iyp * 8 + 2 * s);
        const float2* mym = reinterpret_cast<const float2*>(mu + (size_t)iym * 8 + 2 * s);
        float2 a = *mxp, b = *mxm, c = *myp, d = *mym;
        d0a = (a.x - b.x) * 0.5f; d0b = (a.y - b.y) * 0.5f;
        d1a = (c.x - d.x) * 0.5f; d1b = (c.y - d.y) * 0.5f;
        float2* w0 = reinterpret_cast<float2*>(slotD + 2 * s);
        float2* w1 = reinterpret_cast<float2*>(slotD + 8 + 2 * s);
        float2 v0; v0.x = d0a; v0.y = d0b; *w0 = v0;
        float2 v1; v1.x = d1a; v1.y = d1b; *w1 = v1;
    }

    __syncthreads();   // staging complete

    // ---------------- T rows = Si_rows * dSx ; U rows = Si_rows * dSy ----------------
    float T0[8] = {0}, T1[8] = {0}, U0[8] = {0}, U1[8] = {0};
    #pragma unroll
    for (int j = 0; j < 8; ++j) {
        float a0 = Si[j], a1 = Si[8 + j];
        float bx[8], by[8];
        *reinterpret_cast<float4*>(&bx[0]) = *reinterpret_cast<const float4*>(slotA + j * 8);
        *reinterpret_cast<float4*>(&bx[4]) = *reinterpret_cast<const float4*>(slotA + j * 8 + 4);
        *reinterpret_cast<float4*>(&by[0]) = *reinterpret_cast<const float4*>(slotB + j * 8);
        *reinterpret_cast<float4*>(&by[4]) = *reinterpret_cast<const float4*>(slotB + j * 8 + 4);
        #pragma unroll
        for (int k = 0; k < 8; ++k) {
            T0[k] = fmaf(a0, bx[k], T0[k]);
            T1[k] = fmaf(a1, bx[k], T1[k]);
            U0[k] = fmaf(a0, by[k], U0[k]);
            U1[k] = fmaf(a1, by[k], U1[k]);
        }
    }

    // ---------------- mean terms (uses slotD, never overwritten) ----------------
    float m00, m01, m11;
    {
        float dm0[8], dm1[8];
        *reinterpret_cast<float4*>(&dm0[0]) = *reinterpret_cast<const float4*>(slotD + 0);
        *reinterpret_cast<float4*>(&dm0[4]) = *reinterpret_cast<const float4*>(slotD + 4);
        *reinterpret_cast<float4*>(&dm1[0]) = *reinterpret_cast<const float4*>(slotD + 8);
        *reinterpret_cast<float4*>(&dm1[4]) = *reinterpret_cast<const float4*>(slotD + 12);
        float t00 = 0, t01 = 0, t10 = 0, t11 = 0;  // (Si dmu_n)[row]
        #pragma unroll
        for (int j = 0; j < 8; ++j) {
            t00 = fmaf(Si[j],     dm0[j], t00);
            t01 = fmaf(Si[j],     dm1[j], t01);
            t10 = fmaf(Si[8 + j], dm0[j], t10);
            t11 = fmaf(Si[8 + j], dm1[j], t11);
        }
        m00 = d0a * t00 + d0b * t10;
        m01 = d0a * t01 + d0b * t11;
        m11 = d1a * t01 + d1b * t11;
    }

    __syncthreads();   // all reads of slotA/slotB (dSx/dSy) complete

    // ---------------- write T, U rows back over dSx/dSy ----------------
    {
        float4* wA = reinterpret_cast<float4*>(slotA + s * 16);
        float4* wB = reinterpret_cast<float4*>(slotB + s * 16);
        wA[0] = *reinterpret_cast<const float4*>(&T0[0]);
        wA[1] = *reinterpret_cast<const float4*>(&T0[4]);
        wA[2] = *reinterpret_cast<const float4*>(&T1[0]);
        wA[3] = *reinterpret_cast<const float4*>(&T1[4]);
        wB[0] = *reinterpret_cast<const float4*>(&U0[0]);
        wB[1] = *reinterpret_cast<const float4*>(&U0[4]);
        wB[2] = *reinterpret_cast<const float4*>(&U1[0]);
        wB[3] = *reinterpret_cast<const float4*>(&U1[4]);
    }

    __syncthreads();   // T, U visible

    // ---------------- cov partials: rows (2s,2s+1) dotted with columns (2s,2s+1) ----------------
    float c00 = 0, c01 = 0, c11 = 0;
    #pragma unroll
    for (int k = 0; k < 8; ++k) {
        float ta = slotA[k * 8 + 2 * s];
        float tb = slotA[k * 8 + 2 * s + 1];
        float ua = slotB[k * 8 + 2 * s];
        float ub = slotB[k * 8 + 2 * s + 1];
        c00 = fmaf(T0[k], ta, c00); c00 = fmaf(T1[k], tb, c00);
        c01 = fmaf(T0[k], ua, c01); c01 = fmaf(T1[k], ub, c01);
        c11 = fmaf(U0[k], ua, c11); c11 = fmaf(U1[k], ub, c11);
    }

    // ---------------- combine, 4-lane reduce, write ----------------
    float g0 = m00 + 0.5f * c00;
    float g1 = m01 + 0.5f * c01;
    float g3 = m11 + 0.5f * c11;
    g0 += __shfl_xor(g0, 1); g0 += __shfl_xor(g0, 2);
    g1 += __shfl_xor(g1, 1); g1 += __shfl_xor(g1, 2);
    g3 += __shfl_xor(g3, 1); g3 += __shfl_xor(g3, 2);

    float val = (s == 0) ? g0 : ((s == 3) ? g3 : g1);
    out[(size_t)idx * 4 + s] = val;
}

extern "C" void kernel_launch(void* const* d_in, const int* in_sizes, int n_in,
                              void* d_out, int out_size, void* d_ws, size_t ws_size,
                              hipStream_t stream) {
    const float* mu        = (const float*)d_in[0];
    const float* sigma     = (const float*)d_in[1];
    const float* sigma_inv = (const float*)d_in[2];
    float* out = (float*)d_out;

    // 262144 pixels * 4 threads / 256 = 4096 blocks (divisible by 8 -> bijective swizzle)
    pm4_kernel<<<4096, 256, 0, stream>>>(mu, sigma, sigma_inv, out);
}